// Round 6
// baseline (215.287 us; speedup 1.0000x reference)
//
#include <hip/hip_runtime.h>
#include <stdint.h>

#define BLOCK 256
#define ITEMS 8
#define TILE (BLOCK * ITEMS)   // 2048 elements per block
#define WPB (TILE / 64)        // 32 bitmask words per block
#define MAXSEG 64
#define THRESH 0.1f

typedef unsigned long long u64;

__device__ __forceinline__ int find_seg(const int* rs, int n_seg, int i) {
    // largest s with rs[s] <= i
    int lo = 0, hi = n_seg;
    while (hi - lo > 1) {
        int mid = (lo + hi) >> 1;
        if (rs[mid] <= i) lo = mid; else hi = mid;
    }
    return lo;
}

// Pass 1 (fused): single read of score producing
//   - threshold keep-bitmask (s > THRESH)  [min-tied bits fixed up in k_segfix]
//   - per-block keep counts (threshold-only; fixed up in k_segfix)
//   - per-block packed (min_bits<<32 | idx) partials, <=2 segments per block
__global__ __launch_bounds__(BLOCK) void k_pass1(const float* __restrict__ score,
        const int* __restrict__ row_splits, int n_seg, int n, int nwords,
        u64* __restrict__ partial_val, int* __restrict__ partial_seg,
        u64* __restrict__ bitmask, int* __restrict__ block_counts) {
    __shared__ int rs[MAXSEG + 1];
    __shared__ u64 wval[8];
    __shared__ int wseg[8];
    __shared__ int wsum[4];
    for (int j = threadIdx.x; j <= n_seg; j += BLOCK) rs[j] = row_splits[j];
    __syncthreads();
    int lane = threadIdx.x & 63, wv = threadIdx.x >> 6;
    int wbase = blockIdx.x * TILE + wv * 512;
    u64 m0 = ~0ull, m1 = ~0ull, myword = 0;
    int sf = -1, sl = -1, cnt = 0;
    if (wbase < n) {   // wave-uniform
        int wend = min(n, wbase + 512) - 1;
        sf = find_seg(rs, n_seg, wbase);
        sl = find_seg(rs, n_seg, wend);
        int bval = (sl != sf) ? rs[sf + 1] : 0x7FFFFFFF;
        #pragma unroll
        for (int it = 0; it < 8; it++) {
            int i = wbase + it * 64 + lane;
            bool keep = false;
            if (i < n) {
                float v = score[i];
                u64 p = ((u64)__float_as_uint(v) << 32) | (unsigned int)i;
                if (i < bval) m0 = min(m0, p); else m1 = min(m1, p);
                keep = v > THRESH;
            }
            u64 bal = __ballot(keep);
            if (lane == it) myword = bal;
            cnt += __popcll(bal);
        }
        for (int o = 32; o > 0; o >>= 1) {
            m0 = min(m0, (u64)__shfl_down((unsigned long long)m0, o, 64));
            m1 = min(m1, (u64)__shfl_down((unsigned long long)m1, o, 64));
        }
        if (lane < 8) {
            int w = (wbase >> 6) + lane;
            if (w < nwords) bitmask[w] = myword;
        }
    }
    if (lane == 0) {
        wval[2 * wv] = m0;     wseg[2 * wv] = sf;
        wval[2 * wv + 1] = m1; wseg[2 * wv + 1] = (sl != sf) ? sl : -1;
        wsum[wv] = cnt;
    }
    __syncthreads();
    if (threadIdx.x == 0) {
        int base = blockIdx.x * TILE;
        int endi = min(n, base + TILE) - 1;
        int s0 = find_seg(rs, n_seg, base);
        int s1 = find_seg(rs, n_seg, endi);
        u64 o0 = ~0ull, o1 = ~0ull;
        for (int k = 0; k < 8; k++) {
            if (wseg[k] == s0) o0 = min(o0, wval[k]);
            else if (wseg[k] == s1) o1 = min(o1, wval[k]);
        }
        partial_val[2 * blockIdx.x] = o0;
        partial_seg[2 * blockIdx.x] = s0;
        partial_val[2 * blockIdx.x + 1] = o1;
        partial_seg[2 * blockIdx.x + 1] = (s1 != s0) ? s1 : -1;
        block_counts[blockIdx.x] = wsum[0] + wsum[1] + wsum[2] + wsum[3];
    }
}

// Pass 2: one block PER SEGMENT: reduce block partials -> seg_packed[s]; if
// segmin <= THRESH, set keep bits for min-tied elements (re-reads only the
// matched ~2048-elem tiles).
__global__ __launch_bounds__(BLOCK) void k_segfix(const float* __restrict__ score,
        const int* __restrict__ row_splits, int n_seg, int n,
        const u64* __restrict__ partial_val, const int* __restrict__ partial_seg,
        u64* __restrict__ seg_packed, u64* __restrict__ bitmask,
        int* __restrict__ block_counts) {
    __shared__ u64 wred[4];
    __shared__ int nmatch;
    __shared__ int mlist[64];
    int s = blockIdx.x;
    int lo = row_splits[s], hi = row_splits[s + 1];
    int lane = threadIdx.x & 63, wv = threadIdx.x >> 6;
    if (threadIdx.x == 0) nmatch = 0;
    u64 m = ~0ull;
    int e0 = 0, e1 = -1;
    if (hi > lo) {
        e0 = 2 * (lo / TILE);
        e1 = 2 * ((hi - 1) / TILE) + 1;
        for (int e = e0 + threadIdx.x; e <= e1; e += BLOCK)
            if (partial_seg[e] == s) m = min(m, partial_val[e]);
    }
    for (int o = 32; o > 0; o >>= 1)
        m = min(m, (u64)__shfl_down((unsigned long long)m, o, 64));
    if (lane == 0) wred[wv] = m;
    __syncthreads();
    if (threadIdx.x == 0) {
        u64 r = min(min(wred[0], wred[1]), min(wred[2], wred[3]));
        wred[0] = r;
        seg_packed[s] = r;
    }
    __syncthreads();
    u64 sp = wred[0];
    if (sp == ~0ull) return;
    unsigned int smb = (unsigned int)(sp >> 32);
    if (__uint_as_float(smb) > THRESH) return;   // threshold bit already covers min elems
    for (int e = e0 + threadIdx.x; e <= e1; e += BLOCK) {
        if (partial_seg[e] == s && (unsigned int)(partial_val[e] >> 32) == smb) {
            int k = atomicAdd(&nmatch, 1);   // LDS atomic, rare
            if (k < 64) mlist[k] = e >> 1;
        }
    }
    __syncthreads();
    int nm = min(nmatch, 64);
    for (int k = 0; k < nm; k++) {
        int b = mlist[k];
        int rlo = max(b * TILE, lo);
        int rhi = min(min((b + 1) * TILE, n), hi);
        int c = 0;
        for (int i = rlo + threadIdx.x; i < rhi; i += BLOCK) {
            if (__float_as_uint(score[i]) == smb) {
                atomicOr(&bitmask[i >> 6], 1ull << (i & 63));
                c++;
            }
        }
        for (int o = 32; o > 0; o >>= 1) c += __shfl_down(c, o, 64);
        if (lane == 0 && c) atomicAdd(&block_counts[b], c);
    }
}

// Pass 3 (single block): exclusive scan of block counts -> block_offsets,
// THEN per-thread queries (newrs + rep_pos) via <=32 bitmask popcounts each.
__global__ __launch_bounds__(BLOCK) void k_scanq(const int* __restrict__ counts,
        int* __restrict__ offsets, int nb,
        const int* __restrict__ row_splits, int n_seg, int n, int M,
        const u64* __restrict__ seg_packed, const u64* __restrict__ bitmask,
        int* __restrict__ rep_pos, int* __restrict__ newrs_out) {
    __shared__ int wtot[BLOCK / 64];
    int lane = threadIdx.x & 63, wv = threadIdx.x >> 6;
    {
        int per = (nb + BLOCK - 1) / BLOCK;
        int s = per * threadIdx.x, e = min(nb, s + per);
        int sum = 0;
        for (int i = s; i < e; i++) sum += counts[i];
        int incl = sum;
        for (int o = 1; o < 64; o <<= 1) {
            int t = __shfl_up(incl, o, 64);
            if (lane >= o) incl += t;
        }
        if (lane == 63) wtot[wv] = incl;
        __syncthreads();
        int excl = incl - sum;
        for (int k = 0; k < wv; k++) excl += wtot[k];
        for (int i = s; i < e; i++) { offsets[i] = excl; excl += counts[i]; }
    }
    __syncthreads();
    int nq = 2 * n_seg + 1;
    int q = threadIdx.x;
    if (q < nq) {
        unsigned int uidx;
        if (q <= n_seg) uidx = (unsigned int)row_splits[q];
        else uidx = (unsigned int)(seg_packed[q - (n_seg + 1)] & 0xFFFFFFFFu);
        int result;
        if (uidx >= (unsigned int)n) {
            result = M;
        } else {
            int idx = (int)uidx;
            int b = idx / TILE;
            int wq = idx >> 6;
            int cnt = offsets[b];
            for (int w = b * WPB; w < wq; w++) cnt += __popcll(bitmask[w]);
            if (idx & 63) cnt += __popcll(bitmask[wq] & ((1ull << (idx & 63)) - 1));
            result = cnt;
        }
        if (q <= n_seg) newrs_out[q] = result;
        else rep_pos[q - (n_seg + 1)] = result;
    }
}

// Pass 4: outputs from bitmask only. LDS-staged, phase-aligned int4 stores
// for both back_out and sel_out.
__global__ __launch_bounds__(BLOCK) void k_output(const int* __restrict__ row_splits,
        int n_seg, int n,
        const int* __restrict__ rep_pos, const u64* __restrict__ bitmask,
        const int* __restrict__ block_offsets,
        int* __restrict__ sel_out, int* __restrict__ back_out) {
    __shared__ int rs[MAXSEG + 1];
    __shared__ int srep[MAXSEG];
    __shared__ u64 swords[WPB];
    __shared__ int wpre[WPB];
    __shared__ int stot;
    __shared__ int sbg[TILE];
    __shared__ int skel[TILE];
    for (int j = threadIdx.x; j <= n_seg; j += BLOCK) rs[j] = row_splits[j];
    for (int j = threadIdx.x; j < n_seg; j += BLOCK) srep[j] = rep_pos[j];
    int base = blockIdx.x * TILE;
    int lim = min(TILE, n - base);
    int nw = (lim + 63) >> 6;
    for (int j = threadIdx.x; j < nw; j += BLOCK) swords[j] = bitmask[(base >> 6) + j];
    __syncthreads();
    if (threadIdx.x == 0) {
        int acc = 0;
        for (int k = 0; k < nw; k++) { wpre[k] = acc; acc += __popcll(swords[k]); }
        stot = acc;
    }
    __syncthreads();
    int bo = block_offsets[blockIdx.x];
    int lane = threadIdx.x & 63, wv = threadIdx.x >> 6;
    // fill LDS: sbg (back values) + skel (compacted kept indices, block-local)
    #pragma unroll
    for (int it = 0; it < 8; it++) {
        int widx = wv * 8 + it;
        int i = base + widx * 64 + lane;
        if (i < n) {
            u64 word = swords[widx];
            bool keep = (word >> lane) & 1;
            if (keep) {
                int loc = wpre[widx] + __popcll(word & ((1ull << lane) - 1));
                sbg[i - base] = bo + loc;
                skel[loc] = i;
            } else {
                int seg = find_seg(rs, n_seg, i);
                sbg[i - base] = srep[seg];
            }
        }
    }
    __syncthreads();
    // back_out[base .. base+lim): phase-aligned int4 stores
    {
        uintptr_t addr = (uintptr_t)(back_out + base);
        int st = (int)((4 - ((addr >> 2) & 3)) & 3);
        if (st > lim) st = lim;
        int nv = (lim - st) >> 2;
        for (int t = threadIdx.x; t < nv; t += BLOCK) {
            int j = st + 4 * t;
            *(int4*)(back_out + base + j) = make_int4(sbg[j], sbg[j+1], sbg[j+2], sbg[j+3]);
        }
        for (int j = threadIdx.x; j < st; j += BLOCK) back_out[base + j] = sbg[j];
        for (int j = st + 4 * nv + threadIdx.x; j < lim; j += BLOCK) back_out[base + j] = sbg[j];
    }
    // sel_out[bo .. bo+tot): phase-aligned int4 stores
    {
        int tot = stot;
        uintptr_t addr = (uintptr_t)(sel_out + bo);
        int st = (int)((4 - ((addr >> 2) & 3)) & 3);
        if (st > tot) st = tot;
        int nv = (tot - st) >> 2;
        for (int t = threadIdx.x; t < nv; t += BLOCK) {
            int j = st + 4 * t;
            *(int4*)(sel_out + bo + j) = make_int4(skel[j], skel[j+1], skel[j+2], skel[j+3]);
        }
        for (int j = threadIdx.x; j < st; j += BLOCK) sel_out[bo + j] = skel[j];
        for (int j = st + 4 * nv + threadIdx.x; j < tot; j += BLOCK) sel_out[bo + j] = skel[j];
    }
}

extern "C" void kernel_launch(void* const* d_in, const int* in_sizes, int n_in,
                              void* d_out, int out_size, void* d_ws, size_t ws_size,
                              hipStream_t stream) {
    const float* score = (const float*)d_in[0];
    const int* row_splits = (const int*)d_in[1];
    int n = in_sizes[0];
    int n_seg = in_sizes[1] - 1;
    int M = out_size - (n_seg + 1) - n;
    int nb = (n + TILE - 1) / TILE;
    int nwords = (n + 63) / 64;

    u64* seg_packed   = (u64*)d_ws;                      // 64 u64
    u64* partial_val  = seg_packed + MAXSEG;             // 2*nb u64
    int* partial_seg  = (int*)(partial_val + 2 * nb);    // 2*nb int
    int* rep_pos      = partial_seg + 2 * nb;            // 64 int
    int* block_counts = rep_pos + 64;                    // nb int
    int* block_offsets= block_counts + nb;               // nb int
    uintptr_t bm_addr = (uintptr_t)(block_offsets + nb);
    bm_addr = (bm_addr + 7) & ~(uintptr_t)7;
    u64* bitmask      = (u64*)bm_addr;                   // nwords u64

    int* out = (int*)d_out;
    int* sel_out   = out;
    int* newrs_out = out + M;
    int* back_out  = out + M + (n_seg + 1);

    hipLaunchKernelGGL(k_pass1, dim3(nb), dim3(BLOCK), 0, stream,
                       score, row_splits, n_seg, n, nwords,
                       partial_val, partial_seg, bitmask, block_counts);
    hipLaunchKernelGGL(k_segfix, dim3(n_seg), dim3(BLOCK), 0, stream,
                       score, row_splits, n_seg, n,
                       partial_val, partial_seg, seg_packed, bitmask, block_counts);
    hipLaunchKernelGGL(k_scanq, dim3(1), dim3(BLOCK), 0, stream,
                       block_counts, block_offsets, nb,
                       row_splits, n_seg, n, M, seg_packed, bitmask,
                       rep_pos, newrs_out);
    hipLaunchKernelGGL(k_output, dim3(nb), dim3(BLOCK), 0, stream,
                       row_splits, n_seg, n, rep_pos, bitmask,
                       block_offsets, sel_out, back_out);
}

// Round 7
// 173.346 us; speedup vs baseline: 1.2420x; 1.2420x over previous
//
#include <hip/hip_runtime.h>
#include <stdint.h>

#define BLOCK 256
#define ITEMS 8
#define TILE (BLOCK * ITEMS)   // 2048 elements per block
#define WPB (TILE / 64)        // 32 bitmask words per block
#define MAXSEG 64
#define THRESH 0.1f

typedef unsigned long long u64;

__device__ __forceinline__ int find_seg(const int* rs, int n_seg, int i) {
    // largest s with rs[s] <= i
    int lo = 0, hi = n_seg;
    while (hi - lo > 1) {
        int mid = (lo + hi) >> 1;
        if (rs[mid] <= i) lo = mid; else hi = mid;
    }
    return lo;
}

// Pass 1 (fused): single read of score producing
//   - threshold keep-bitmask (s > THRESH)  [min-tied bits fixed up in k_segfix]
//   - per-block keep counts (threshold-only; fixed up in k_segfix)
//   - per-block packed (min_bits<<32 | idx) partials, <=2 segments per block
// Loads: 2x dwordx4 per thread (elements 8t..8t+7); keep bits assembled
// per-lane byte -> 64-bit words via 3x shfl_xor (vs 8 ballots/8 scalar loads).
__global__ __launch_bounds__(BLOCK) void k_pass1(const float* __restrict__ score,
        const int* __restrict__ row_splits, int n_seg, int n, int nwords,
        u64* __restrict__ partial_val, int* __restrict__ partial_seg,
        u64* __restrict__ bitmask, int* __restrict__ block_counts) {
    __shared__ int rs[MAXSEG + 1];
    __shared__ u64 wval[8];
    __shared__ int wseg[8];
    __shared__ int wsum[4];
    for (int j = threadIdx.x; j <= n_seg; j += BLOCK) rs[j] = row_splits[j];
    __syncthreads();
    int lane = threadIdx.x & 63, wv = threadIdx.x >> 6;
    int wbase = blockIdx.x * TILE + wv * 512;
    u64 m0 = ~0ull, m1 = ~0ull;
    int sf = -1, sl = -1, cnt = 0;
    if (wbase < n) {   // wave-uniform
        int wend = min(n, wbase + 512) - 1;
        sf = find_seg(rs, n_seg, wbase);
        sl = find_seg(rs, n_seg, wend);
        int bval = (sl != sf) ? rs[sf + 1] : 0x7FFFFFFF;
        int tbase = wbase + lane * 8;
        unsigned int kbyte = 0;
        if (tbase < n) {
            float v[8];
            if (tbase + 8 <= n) {
                float4 f0 = *(const float4*)(score + tbase);
                float4 f1 = *(const float4*)(score + tbase + 4);
                v[0]=f0.x; v[1]=f0.y; v[2]=f0.z; v[3]=f0.w;
                v[4]=f1.x; v[5]=f1.y; v[6]=f1.z; v[7]=f1.w;
            } else {
                for (int j = 0; j < 8; j++) v[j] = (tbase + j < n) ? score[tbase + j] : 1.0f;
            }
            #pragma unroll
            for (int j = 0; j < 8; j++) {
                int i = tbase + j;
                if (i < n) {
                    u64 p = ((u64)__float_as_uint(v[j]) << 32) | (unsigned int)i;
                    if (i < bval) m0 = min(m0, p); else m1 = min(m1, p);
                    if (v[j] > THRESH) kbyte |= 1u << j;
                }
            }
            cnt = __popc(kbyte);
        }
        // assemble 64-bit words within groups of 8 lanes
        u64 acc = ((u64)kbyte) << (8 * (lane & 7));
        acc |= __shfl_xor((unsigned long long)acc, 1, 64);
        acc |= __shfl_xor((unsigned long long)acc, 2, 64);
        acc |= __shfl_xor((unsigned long long)acc, 4, 64);
        int src = (lane < 8) ? (8 * lane) : lane;
        u64 myword = __shfl((unsigned long long)acc, src, 64);
        for (int o = 32; o > 0; o >>= 1) {
            m0 = min(m0, (u64)__shfl_down((unsigned long long)m0, o, 64));
            m1 = min(m1, (u64)__shfl_down((unsigned long long)m1, o, 64));
            cnt += __shfl_down(cnt, o, 64);
        }
        if (lane < 8) {
            int w = (wbase >> 6) + lane;
            if (w < nwords) bitmask[w] = myword;
        }
    }
    if (lane == 0) {
        wval[2 * wv] = m0;     wseg[2 * wv] = sf;
        wval[2 * wv + 1] = m1; wseg[2 * wv + 1] = (sl != sf) ? sl : -1;
        wsum[wv] = (wbase < n) ? cnt : 0;
    }
    __syncthreads();
    if (threadIdx.x == 0) {
        int base = blockIdx.x * TILE;
        int endi = min(n, base + TILE) - 1;
        int s0 = find_seg(rs, n_seg, base);
        int s1 = find_seg(rs, n_seg, endi);
        u64 o0 = ~0ull, o1 = ~0ull;
        for (int k = 0; k < 8; k++) {
            if (wseg[k] == s0) o0 = min(o0, wval[k]);
            else if (wseg[k] == s1) o1 = min(o1, wval[k]);
        }
        partial_val[2 * blockIdx.x] = o0;
        partial_seg[2 * blockIdx.x] = s0;
        partial_val[2 * blockIdx.x + 1] = o1;
        partial_seg[2 * blockIdx.x + 1] = (s1 != s0) ? s1 : -1;
        block_counts[blockIdx.x] = wsum[0] + wsum[1] + wsum[2] + wsum[3];
    }
}

// Pass 2: one block PER SEGMENT: reduce block partials -> seg_packed[s]; if
// segmin <= THRESH, set keep bits for min-tied elements (re-reads only the
// matched ~2048-elem tiles).
__global__ __launch_bounds__(BLOCK) void k_segfix(const float* __restrict__ score,
        const int* __restrict__ row_splits, int n_seg, int n,
        const u64* __restrict__ partial_val, const int* __restrict__ partial_seg,
        u64* __restrict__ seg_packed, u64* __restrict__ bitmask,
        int* __restrict__ block_counts) {
    __shared__ u64 wred[4];
    __shared__ int nmatch;
    __shared__ int mlist[64];
    int s = blockIdx.x;
    int lo = row_splits[s], hi = row_splits[s + 1];
    int lane = threadIdx.x & 63, wv = threadIdx.x >> 6;
    if (threadIdx.x == 0) nmatch = 0;
    u64 m = ~0ull;
    int e0 = 0, e1 = -1;
    if (hi > lo) {
        e0 = 2 * (lo / TILE);
        e1 = 2 * ((hi - 1) / TILE) + 1;
        for (int e = e0 + threadIdx.x; e <= e1; e += BLOCK)
            if (partial_seg[e] == s) m = min(m, partial_val[e]);
    }
    for (int o = 32; o > 0; o >>= 1)
        m = min(m, (u64)__shfl_down((unsigned long long)m, o, 64));
    if (lane == 0) wred[wv] = m;
    __syncthreads();
    if (threadIdx.x == 0) {
        u64 r = min(min(wred[0], wred[1]), min(wred[2], wred[3]));
        wred[0] = r;
        seg_packed[s] = r;
    }
    __syncthreads();
    u64 sp = wred[0];
    if (sp == ~0ull) return;
    unsigned int smb = (unsigned int)(sp >> 32);
    if (__uint_as_float(smb) > THRESH) return;   // threshold bit already covers min elems
    for (int e = e0 + threadIdx.x; e <= e1; e += BLOCK) {
        if (partial_seg[e] == s && (unsigned int)(partial_val[e] >> 32) == smb) {
            int k = atomicAdd(&nmatch, 1);   // LDS atomic, rare
            if (k < 64) mlist[k] = e >> 1;
        }
    }
    __syncthreads();
    int nm = min(nmatch, 64);
    for (int k = 0; k < nm; k++) {
        int b = mlist[k];
        int rlo = max(b * TILE, lo);
        int rhi = min(min((b + 1) * TILE, n), hi);
        int c = 0;
        for (int i = rlo + threadIdx.x; i < rhi; i += BLOCK) {
            if (__float_as_uint(score[i]) == smb) {
                atomicOr(&bitmask[i >> 6], 1ull << (i & 63));
                c++;
            }
        }
        for (int o = 32; o > 0; o >>= 1) c += __shfl_down(c, o, 64);
        if (lane == 0 && c) atomicAdd(&block_counts[b], c);
    }
}

// Pass 3 (single block): exclusive scan of block counts -> block_offsets,
// THEN per-thread queries (newrs + rep_pos) via <=32 bitmask popcounts each.
__global__ __launch_bounds__(BLOCK) void k_scanq(const int* __restrict__ counts,
        int* __restrict__ offsets, int nb,
        const int* __restrict__ row_splits, int n_seg, int n, int M,
        const u64* __restrict__ seg_packed, const u64* __restrict__ bitmask,
        int* __restrict__ rep_pos, int* __restrict__ newrs_out) {
    __shared__ int wtot[BLOCK / 64];
    int lane = threadIdx.x & 63, wv = threadIdx.x >> 6;
    {
        int per = (nb + BLOCK - 1) / BLOCK;
        int s = per * threadIdx.x, e = min(nb, s + per);
        int sum = 0;
        for (int i = s; i < e; i++) sum += counts[i];
        int incl = sum;
        for (int o = 1; o < 64; o <<= 1) {
            int t = __shfl_up(incl, o, 64);
            if (lane >= o) incl += t;
        }
        if (lane == 63) wtot[wv] = incl;
        __syncthreads();
        int excl = incl - sum;
        for (int k = 0; k < wv; k++) excl += wtot[k];
        for (int i = s; i < e; i++) { offsets[i] = excl; excl += counts[i]; }
    }
    __syncthreads();
    int nq = 2 * n_seg + 1;
    int q = threadIdx.x;
    if (q < nq) {
        unsigned int uidx;
        if (q <= n_seg) uidx = (unsigned int)row_splits[q];
        else uidx = (unsigned int)(seg_packed[q - (n_seg + 1)] & 0xFFFFFFFFu);
        int result;
        if (uidx >= (unsigned int)n) {
            result = M;
        } else {
            int idx = (int)uidx;
            int b = idx / TILE;
            int wq = idx >> 6;
            int cnt = offsets[b];
            for (int w = b * WPB; w < wq; w++) cnt += __popcll(bitmask[w]);
            if (idx & 63) cnt += __popcll(bitmask[wq] & ((1ull << (idx & 63)) - 1));
            result = cnt;
        }
        if (q <= n_seg) newrs_out[q] = result;
        else rep_pos[q - (n_seg + 1)] = result;
    }
}

// Pass 4: outputs from bitmask. back values computed in registers for 4
// consecutive phase-aligned positions -> dwordx4 stores. sel indices staged in
// LDS with slot offset so vector reads are aligned ds_read_b128 (conflict-free).
// Assumes <=1 segment boundary per 2048-elem block (seg len >> 2048 here).
__global__ __launch_bounds__(BLOCK) void k_output(const int* __restrict__ row_splits,
        int n_seg, int n,
        const int* __restrict__ rep_pos, const u64* __restrict__ bitmask,
        const int* __restrict__ block_offsets,
        int* __restrict__ sel_out, int* __restrict__ back_out) {
    __shared__ int rs[MAXSEG + 1];
    __shared__ u64 swords[WPB];
    __shared__ int wpre[WPB];
    __shared__ int shead[6];   // bval, rep0, rep1, tot
    __shared__ alignas(16) int skel[TILE + 8];
    for (int j = threadIdx.x; j <= n_seg; j += BLOCK) rs[j] = row_splits[j];
    int base = blockIdx.x * TILE;
    int lim = min(TILE, n - base);
    int nw = (lim + 63) >> 6;
    for (int j = threadIdx.x; j < nw; j += BLOCK) swords[j] = bitmask[(base >> 6) + j];
    __syncthreads();
    if (threadIdx.x == 0) {
        int acc = 0;
        for (int k = 0; k < nw; k++) { wpre[k] = acc; acc += __popcll(swords[k]); }
        int s0 = find_seg(rs, n_seg, base);
        int s1 = find_seg(rs, n_seg, base + lim - 1);
        shead[0] = (s1 != s0) ? rs[s0 + 1] : 0x7FFFFFFF;
        shead[1] = rep_pos[s0];
        shead[2] = rep_pos[s1];
        shead[3] = acc;
    }
    __syncthreads();
    int bval = shead[0], rep0 = shead[1], rep1 = shead[2], tot = shead[3];
    int bo = block_offsets[blockIdx.x];
    // phases
    int st_b = (int)((4 - ((((uintptr_t)(back_out + base)) >> 2) & 3)) & 3);
    if (st_b > lim) st_b = lim;
    int st_s = (int)((4 - ((((uintptr_t)(sel_out + bo)) >> 2) & 3)) & 3);
    if (st_s > tot) st_s = tot;
    int selpad = 4 - st_s;          // skel slot = (pos - bo) + selpad; first aligned slot = 4

    // main: full int4 groups of back_out; also stage kept indices into skel
    int ngroups = (lim - st_b) >> 2;
    for (int g = threadIdx.x; g < ngroups; g += BLOCK) {
        int j0 = st_b + 4 * g;
        int vals[4];
        #pragma unroll
        for (int k = 0; k < 4; k++) {
            int j = j0 + k;
            int widx = j >> 6, r = j & 63;
            u64 w = swords[widx];
            int i = base + j;
            if ((w >> r) & 1) {
                int pos = bo + wpre[widx] + __popcll(w & ((1ull << r) - 1));
                vals[k] = pos;
                skel[pos - bo + selpad] = i;
            } else {
                vals[k] = (i >= bval) ? rep1 : rep0;
            }
        }
        *(int4*)(back_out + base + j0) = make_int4(vals[0], vals[1], vals[2], vals[3]);
    }
    // edges of back region (<=3 head, <=3 tail)
    for (int j = threadIdx.x; j < st_b; j += BLOCK) {
        int widx = j >> 6, r = j & 63;
        u64 w = swords[widx];
        int i = base + j, val;
        if ((w >> r) & 1) {
            int pos = bo + wpre[widx] + __popcll(w & ((1ull << r) - 1));
            val = pos;
            skel[pos - bo + selpad] = i;
        } else val = (i >= bval) ? rep1 : rep0;
        back_out[i] = val;
    }
    for (int j = st_b + 4 * ngroups + threadIdx.x; j < lim; j += BLOCK) {
        int widx = j >> 6, r = j & 63;
        u64 w = swords[widx];
        int i = base + j, val;
        if ((w >> r) & 1) {
            int pos = bo + wpre[widx] + __popcll(w & ((1ull << r) - 1));
            val = pos;
            skel[pos - bo + selpad] = i;
        } else val = (i >= bval) ? rep1 : rep0;
        back_out[i] = val;
    }
    __syncthreads();
    // sel_out: aligned int4 stores fed by aligned ds_read_b128
    int nvg = (tot - st_s) >> 2;
    for (int g = threadIdx.x; g < nvg; g += BLOCK) {
        int4 v = *(const int4*)&skel[4 + 4 * g];
        *(int4*)(sel_out + bo + st_s + 4 * g) = v;
    }
    for (int j = threadIdx.x; j < st_s; j += BLOCK) sel_out[bo + j] = skel[j + selpad];
    for (int j = st_s + 4 * nvg + threadIdx.x; j < tot; j += BLOCK) sel_out[bo + j] = skel[j + selpad];
}

extern "C" void kernel_launch(void* const* d_in, const int* in_sizes, int n_in,
                              void* d_out, int out_size, void* d_ws, size_t ws_size,
                              hipStream_t stream) {
    const float* score = (const float*)d_in[0];
    const int* row_splits = (const int*)d_in[1];
    int n = in_sizes[0];
    int n_seg = in_sizes[1] - 1;
    int M = out_size - (n_seg + 1) - n;
    int nb = (n + TILE - 1) / TILE;
    int nwords = (n + 63) / 64;

    u64* seg_packed   = (u64*)d_ws;                      // 64 u64
    u64* partial_val  = seg_packed + MAXSEG;             // 2*nb u64
    int* partial_seg  = (int*)(partial_val + 2 * nb);    // 2*nb int
    int* rep_pos      = partial_seg + 2 * nb;            // 64 int
    int* block_counts = rep_pos + 64;                    // nb int
    int* block_offsets= block_counts + nb;               // nb int
    uintptr_t bm_addr = (uintptr_t)(block_offsets + nb);
    bm_addr = (bm_addr + 7) & ~(uintptr_t)7;
    u64* bitmask      = (u64*)bm_addr;                   // nwords u64

    int* out = (int*)d_out;
    int* sel_out   = out;
    int* newrs_out = out + M;
    int* back_out  = out + M + (n_seg + 1);

    hipLaunchKernelGGL(k_pass1, dim3(nb), dim3(BLOCK), 0, stream,
                       score, row_splits, n_seg, n, nwords,
                       partial_val, partial_seg, bitmask, block_counts);
    hipLaunchKernelGGL(k_segfix, dim3(n_seg), dim3(BLOCK), 0, stream,
                       score, row_splits, n_seg, n,
                       partial_val, partial_seg, seg_packed, bitmask, block_counts);
    hipLaunchKernelGGL(k_scanq, dim3(1), dim3(BLOCK), 0, stream,
                       block_counts, block_offsets, nb,
                       row_splits, n_seg, n, M, seg_packed, bitmask,
                       rep_pos, newrs_out);
    hipLaunchKernelGGL(k_output, dim3(nb), dim3(BLOCK), 0, stream,
                       row_splits, n_seg, n, rep_pos, bitmask,
                       block_offsets, sel_out, back_out);
}